// Round 12
// baseline (508.994 us; speedup 1.0000x reference)
//
#include <hip/hip_runtime.h>

// B=16, N=1024 (=32x32), DIM=768, HEADS=8, CH=96, HIDDEN=3072.
#define BATCH 16
#define SEQ   1024
#define DIM   768
#define NHEAD 8
#define CHD   96
#define HID   3072
#define MTOT  (BATCH * SEQ)   // 16384

using u16 = unsigned short;
typedef __attribute__((ext_vector_type(8))) short bf16x8;   // 8 bf16 = 4 VGPRs
typedef __attribute__((ext_vector_type(4))) float f32x4;

#define AS1 __attribute__((address_space(1)))
#define AS3 __attribute__((address_space(3)))

__device__ inline float bf2f(u16 u) {
    union { unsigned int i; float f; } v; v.i = ((unsigned int)u) << 16; return v.f;
}
__device__ inline u16 f2bf(float f) {
    union { float f; unsigned int i; } v; v.f = f;
    unsigned int r = v.i + 0x7FFFu + ((v.i >> 16) & 1u);
    return (u16)(r >> 16);
}

__device__ inline void gld16(const void* g, void* l) {
    __builtin_amdgcn_global_load_lds((AS1 const void*)g, (AS3 void*)l, 16, 0, 0);
}

// ---------------------------------------------------------------------------
// 128x128 bf16 MFMA GEMM, m97 structure (r12): BK=32, SINGLE-buffered 16 KB
// LDS, plain 2-barrier K-loop, relying on MULTI-BLOCK implicit overlap
// (~5 blocks/CU by VGPR; m114/m97: co-resident blocks cover each other's
// barrier/drain stalls — the mechanism none of the 1-block/CU deep-pipeline
// variants could use). XCD-chunked swizzle (fetch 307->~120MB, r4-proven) +
// 0-conflict folded-row LDS swizzle (r5/r7/r8-PMC-proven).
//   C[m,n] = sum_k A[m,k]*B[n,k]; n < N1 -> C1 (+bias[n]), else C2 (+0).
// 256 thr = 4 waves (2x2), per-wave 64x64 output, acc[4][4] f32x4.
// LDS layout per operand (128 rows x 32 k = 8 KB): physical row p = r&63
// (128 B: 8 chunks of 16B); chunk c = (r>>6)*4 + (k>>3) stored at slot
// c^(p&7). 16-lane frag-read group: p = base+lrow -> slots distinct -> banks
// covered once per 8 lanes = 2-way = free [m136]. Staged linearly
// (base + lane*16B) via pre-swizzled global source (rule #21):
// thread t, issue q: p = 32q + (t>>3), slot = t&7, c = slot^(p&7)
// (32&7=0 -> c identical for both issues), src row = (c>>2)*64 + p,
// src k = (c&3)*8; dst elem = q*2048 + t*8  (= uniform base + lane*8).
// Epilogue: 2-pass LDS transpose (64 rows x 128 cols = 16 KB per pass) ->
// coalesced bf16x8 stores.
// ---------------------------------------------------------------------------
__global__ __launch_bounds__(256) void gemm128(const u16* __restrict__ A,
                                               const u16* __restrict__ B,
                                               const float* __restrict__ bias,
                                               u16* __restrict__ C1, int N1,
                                               u16* __restrict__ C2,
                                               int M, int N, int K) {
    __shared__ u16 lds[8192];            // 16 KB: A [0,4096), B [4096,8192)
    const int tid = threadIdx.x;
    const int lane = tid & 63;
    const int wave = tid >> 6;
    const int wm = (wave >> 1) << 6;     // 0 or 64
    const int wn = (wave & 1) << 6;      // 0 or 64

    // XCD-chunked bijective swizzle (caller guarantees nwg % 8 == 0).
    const int nwg = gridDim.x;
    const int wg = blockIdx.x;
    const int lid = (wg & 7) * (nwg >> 3) + (wg >> 3);
    const int nbx = N >> 7;
    const int mb = lid / nbx, nb = lid - mb * nbx;
    const int m0 = mb << 7, n0 = nb << 7;

    // ---- staging geometry (pre-swizzled source; LDS written linearly) ----
    const int sp = tid >> 3;             // 0..31 (physical row, q=0)
    const int sc = (tid & 7) ^ (sp & 7); // logical chunk (same for q=1)
    const int sh = sc >> 2;              // A/B half (row>>6)
    const int skc = (sc & 3) << 3;       // k elems
    const u16* pa0 = A + (size_t)(m0 + (sh << 6) + sp) * K + skc;
    const u16* pa1 = A + (size_t)(m0 + (sh << 6) + sp + 32) * K + skc;
    const u16* pb0 = B + (size_t)(n0 + (sh << 6) + sp) * K + skc;
    const u16* pb1 = B + (size_t)(n0 + (sh << 6) + sp + 32) * K + skc;

    // ---- fragment read geometry (constant per iteration) ----
    const int lrow = lane & 15;
    const int kg = lane >> 4;            // 0..3
    const int hA = wm >> 6, hB = wn >> 6;
    const int offA = ((hA * 4 + kg) ^ (lrow & 7)) << 3;   // elem offset in row
    const int offB = ((hB * 4 + kg) ^ (lrow & 7)) << 3;

    f32x4 acc[4][4] = {};

    for (int k0 = 0; k0 < K; k0 += 32) {
        gld16(pa0 + k0, &lds[tid * 8]);
        gld16(pa1 + k0, &lds[2048 + tid * 8]);
        gld16(pb0 + k0, &lds[4096 + tid * 8]);
        gld16(pb1 + k0, &lds[6144 + tid * 8]);
        __syncthreads();                 // compiler drains vmcnt here

        bf16x8 af[4], bf[4];
#pragma unroll
        for (int i = 0; i < 4; ++i)
            af[i] = *(const bf16x8*)&lds[(i * 16 + lrow) * 64 + offA];
#pragma unroll
        for (int j = 0; j < 4; ++j)
            bf[j] = *(const bf16x8*)&lds[4096 + (j * 16 + lrow) * 64 + offB];
#pragma unroll
        for (int i = 0; i < 4; ++i)
#pragma unroll
            for (int j = 0; j < 4; ++j)
                acc[i][j] = __builtin_amdgcn_mfma_f32_16x16x32_bf16(af[i], bf[j], acc[i][j], 0, 0, 0);
        __syncthreads();                 // protect LDS before next stage
    }

    // ---- epilogue: 2-pass LDS transpose -> coalesced bf16x8 stores ----
    // C/D frag layout: col = lane&15, row = (lane>>4)*4 + reg  [m89/m91]
    const int crow = (lane >> 4) << 2, ccol = lane & 15;
    const int N2 = N - N1;
#pragma unroll
    for (int p = 0; p < 2; ++p) {
        if ((wave >> 1) == p) {          // waves owning rows p*64..p*64+63
#pragma unroll
            for (int i = 0; i < 4; ++i) {
#pragma unroll
                for (int j = 0; j < 4; ++j) {
                    const int col = wn + j * 16 + ccol;
                    const int gn = n0 + col;
                    const float bv = (gn < N1 && bias) ? bias[gn] : 0.f;
#pragma unroll
                    for (int r = 0; r < 4; ++r) {
                        const int lr = i * 16 + crow + r;   // 0..63
                        lds[lr * 128 + (((col >> 3) ^ (lr & 7)) << 3) + (col & 7)] =
                            f2bf(acc[i][j][r] + bv);
                    }
                }
            }
        }
        __syncthreads();
#pragma unroll
        for (int k = 0; k < 4; ++k) {
            const int c = tid + (k << 8);       // 0..1023
            const int row = c >> 4, s = c & 15;
            bf16x8 v = *(const bf16x8*)&lds[row * 128 + ((s ^ (row & 7)) << 3)];
            const int gm = m0 + p * 64 + row, gnb = n0 + (s << 3);
            if (gnb < N1) *(bf16x8*)&C1[(size_t)gm * N1 + gnb] = v;
            else          *(bf16x8*)&C2[(size_t)gm * N2 + gnb - N1] = v;
        }
        __syncthreads();
    }
}

// One-shot fp32 -> bf16 convert of all four inputs (x, Wq, fc1w, fc2w).
__global__ __launch_bounds__(256) void cvt_all(const float* __restrict__ x,
                                               const float* __restrict__ Wq,
                                               const float* __restrict__ w1,
                                               const float* __restrict__ w2,
                                               u16* __restrict__ xb,
                                               u16* __restrict__ Wqb,
                                               u16* __restrict__ w1b,
                                               u16* __restrict__ w2b) {
    const int E0 = MTOT * DIM / 4;
    const int E1 = E0 + DIM * DIM / 4;
    const int E2 = E1 + HID * DIM / 4;
    const int E3 = E2 + DIM * HID / 4;
    int i = blockIdx.x * 256 + threadIdx.x;
    if (i >= E3) return;
    const float* in; u16* out; int k;
    if (i < E0)      { in = x;  out = xb;  k = i; }
    else if (i < E1) { in = Wq; out = Wqb; k = i - E0; }
    else if (i < E2) { in = w1; out = w1b; k = i - E1; }
    else             { in = w2; out = w2b; k = i - E2; }
    float4 v = reinterpret_cast<const float4*>(in)[k];
    ushort4 o;
    o.x = f2bf(v.x); o.y = f2bf(v.y); o.z = f2bf(v.z); o.w = f2bf(v.w);
    reinterpret_cast<ushort4*>(out)[k] = o;
}

// Column-wise (over n) online softmax stats (max, sumexp) per (b, j). bf16 in.
__global__ __launch_bounds__(256) void colsm_stats(const u16* __restrict__ X,
                                                   float* __restrict__ Mo,
                                                   float* __restrict__ So) {
    const int tid = threadIdx.x, lane = tid & 63, chunk = tid >> 6;
    const int b = blockIdx.y;
    const int j = blockIdx.x * 64 + lane;
    const u16* p = X + (size_t)b * SEQ * DIM + j;
    float m = -3.0e38f, s = 0.f;
    const int nEnd = (chunk + 1) << 8;
    for (int n = chunk << 8; n < nEnd; ++n) {
        float raw = bf2f(p[(size_t)n * DIM]);
        float nm = fmaxf(m, raw);
        s = s * __expf(m - nm) + __expf(raw - nm);
        m = nm;
    }
    __shared__ float ms[4][64], ss[4][64];
    ms[chunk][lane] = m; ss[chunk][lane] = s;
    __syncthreads();
    if (tid < 64) {
        float M = fmaxf(fmaxf(ms[0][lane], ms[1][lane]), fmaxf(ms[2][lane], ms[3][lane]));
        float S = ss[0][lane] * __expf(ms[0][lane] - M) + ss[1][lane] * __expf(ms[1][lane] - M) +
                  ss[2][lane] * __expf(ms[2][lane] - M) + ss[3][lane] * __expf(ms[3][lane] - M);
        Mo[b * DIM + j] = M;
        So[b * DIM + j] = S;
    }
}

// kp[b,h,n] = mean_c softmax_n(x)[b,n,h*96+c]   (bf16 x)
__global__ __launch_bounds__(256) void kp_k(const u16* __restrict__ x,
                                            const float* __restrict__ Mx,
                                            const float* __restrict__ Sx,
                                            float* __restrict__ kp) {
    const int n = blockIdx.x, b = blockIdx.y, tid = threadIdx.x;
    const u16* row = x + ((size_t)b * SEQ + n) * DIM;
    const int h = tid >> 5, c0 = tid & 31;
    const float* Mrow = Mx + b * DIM;
    const float* Srow = Sx + b * DIM;
    float s = 0.f;
#pragma unroll
    for (int q = 0; q < 3; ++q) {
        const int j = h * CHD + c0 + (q << 5);
        s += __expf(bf2f(row[j]) - Mrow[j]) / Srow[j];
    }
#pragma unroll
    for (int o = 16; o; o >>= 1) s += __shfl_down(s, o, 32);
    if (c0 == 0) kp[((size_t)b * NHEAD + h) * SEQ + n] = s * (1.f / (float)CHD);
}

// Fused column-softmax(Q) + gated attention:
// attn[b,j] = temp[h] * sigmoid( (sum_n exp(Q-M)*kp) / (sum_n exp(Q-M)) )
__global__ __launch_bounds__(256) void qattn_k(const u16* __restrict__ Q,
                                               const float* __restrict__ kp,
                                               const float* __restrict__ temp,
                                               float* __restrict__ attnv) {
    const int tid = threadIdx.x, lane = tid & 63, chunk = tid >> 6;
    const int b = blockIdx.y;
    const int j = blockIdx.x * 64 + lane;
    const int h = j / CHD;
    const u16* qp = Q + (size_t)b * SEQ * DIM + j;
    const float* kpp = kp + ((size_t)b * NHEAD + h) * SEQ;
    float m = -3.0e38f, s = 0.f, a = 0.f;
    const int nEnd = (chunk + 1) << 8;
    for (int n = chunk << 8; n < nEnd; ++n) {
        float q = bf2f(qp[(size_t)n * DIM]);
        float nm = fmaxf(m, q);
        float sc = __expf(m - nm), e = __expf(q - nm);
        s = s * sc + e;
        a = a * sc + e * kpp[n];
        m = nm;
    }
    __shared__ float ms[4][64], ss[4][64], as_[4][64];
    ms[chunk][lane] = m; ss[chunk][lane] = s; as_[chunk][lane] = a;
    __syncthreads();
    if (tid < 64) {
        float M = fmaxf(fmaxf(ms[0][lane], ms[1][lane]), fmaxf(ms[2][lane], ms[3][lane]));
        float S = 0.f, A = 0.f;
#pragma unroll
        for (int c = 0; c < 4; ++c) {
            float sc = __expf(ms[c][lane] - M);
            S += ss[c][lane] * sc;
            A += as_[c][lane] * sc;
        }
        float z = A / S;
        attnv[b * DIM + j] = temp[h] / (1.f + __expf(-z));
    }
}

// Depthwise 3x3 + residual + gamma, vectorized: 8 channels x 8 x-positions
// per thread. Residual/bias folded into weights.
__global__ __launch_bounds__(128) void dwconv_v(const u16* __restrict__ h1,
                                                const float* __restrict__ w,
                                                const float* __restrict__ dwb,
                                                const float* __restrict__ gamma,
                                                u16* __restrict__ h2) {
    const int g = blockIdx.x * 128 + threadIdx.x;   // ch8 group, 0..383
    const int y = blockIdx.y >> 2;                  // 0..31
    const int xw0 = (blockIdx.y & 3) << 3;          // 0,8,16,24
    const int b = blockIdx.z;
    const int ch0 = g << 3;

    float wreg[8][9], bias2[8];
#pragma unroll
    for (int c = 0; c < 8; ++c) {
        const float gm = gamma[ch0 + c];
#pragma unroll
        for (int k = 0; k < 9; ++k) wreg[c][k] = gm * w[(ch0 + c) * 9 + k];
        wreg[c][4] += 1.0f;                 // residual fold (center tap)
        bias2[c] = gm * dwb[ch0 + c];
    }

    float acc[8][8];
#pragma unroll
    for (int xo = 0; xo < 8; ++xo)
#pragma unroll
        for (int c = 0; c < 8; ++c) acc[xo][c] = bias2[c];

    const u16* base = h1 + (size_t)b * SEQ * HID + ch0;
#pragma unroll
    for (int dy = 0; dy < 3; ++dy) {
        const int yy = y + dy - 1;
        if ((unsigned)yy > 31u) continue;           // wave-uniform
#pragma unroll
        for (int cr = -1; cr <= 8; ++cr) {          // column rel to xw0
            const int col = xw0 + cr;
            if ((unsigned)col > 31u) continue;      // wave-uniform
            const uint4 v = *reinterpret_cast<const uint4*>(
                base + (size_t)((yy << 5) + col) * HID);
            float f[8];
            f[0] = bf2f((u16)(v.x & 0xffff)); f[1] = bf2f((u16)(v.x >> 16));
            f[2] = bf2f((u16)(v.y & 0xffff)); f[3] = bf2f((u16)(v.y >> 16));
            f[4] = bf2f((u16)(v.z & 0xffff)); f[5] = bf2f((u16)(v.z >> 16));
            f[6] = bf2f((u16)(v.w & 0xffff)); f[7] = bf2f((u16)(v.w >> 16));
            const int xlo = cr > 0 ? cr - 1 : 0;
            const int xhi = cr < 7 ? cr + 1 : 7;
#pragma unroll
            for (int xo = 0; xo < 8; ++xo) {
                if (xo < xlo || xo > xhi) continue; // compile-time after unroll
                const int dx = cr - xo + 1;
#pragma unroll
                for (int c = 0; c < 8; ++c)
                    acc[xo][c] += f[c] * wreg[c][dy * 3 + dx];
            }
        }
    }

#pragma unroll
    for (int xo = 0; xo < 8; ++xo) {
        const int n = (y << 5) + xw0 + xo;
        uint4 o;
        o.x = (unsigned)f2bf(acc[xo][0]) | ((unsigned)f2bf(acc[xo][1]) << 16);
        o.y = (unsigned)f2bf(acc[xo][2]) | ((unsigned)f2bf(acc[xo][3]) << 16);
        o.z = (unsigned)f2bf(acc[xo][4]) | ((unsigned)f2bf(acc[xo][5]) << 16);
        o.w = (unsigned)f2bf(acc[xo][6]) | ((unsigned)f2bf(acc[xo][7]) << 16);
        *reinterpret_cast<uint4*>(h2 + ((size_t)b * SEQ + n) * HID + ch0) = o;
    }
}

// LayerNorm(768) then out[b,n,j] = attn[b,j]*v ; out2[b,h,n,c] = same value.
__global__ __launch_bounds__(256) void ln_out_k(const u16* __restrict__ vpre,
                                                const float* __restrict__ lnw,
                                                const float* __restrict__ lnb,
                                                const float* __restrict__ attnv,
                                                float* __restrict__ out,
                                                float* __restrict__ out2) {
    const int n = blockIdx.x, b = blockIdx.y, tid = threadIdx.x;
    __shared__ float red[4];
    const u16* row = vpre + ((size_t)b * SEQ + n) * DIM;
    float v[3];
    float s = 0.f;
#pragma unroll
    for (int q = 0; q < 3; ++q) { v[q] = bf2f(row[tid + (q << 8)]); s += v[q]; }
#pragma unroll
    for (int o = 32; o; o >>= 1) s += __shfl_down(s, o, 64);
    if ((tid & 63) == 0) red[tid >> 6] = s;
    __syncthreads();
    const float mu = (red[0] + red[1] + red[2] + red[3]) * (1.f / (float)DIM);
    __syncthreads();
    float vs = 0.f;
#pragma unroll
    for (int q = 0; q < 3; ++q) { float d = v[q] - mu; vs += d * d; }
#pragma unroll
    for (int o = 32; o; o >>= 1) vs += __shfl_down(vs, o, 64);
    if ((tid & 63) == 0) red[tid >> 6] = vs;
    __syncthreads();
    const float rstd = rsqrtf((red[0] + red[1] + red[2] + red[3]) * (1.f / (float)DIM) + 1e-5f);
    const float* at = attnv + b * DIM;
    float* orow = out + ((size_t)b * SEQ + n) * DIM;
#pragma unroll
    for (int q = 0; q < 3; ++q) {
        int j = tid + (q << 8);
        float o = (v[q] - mu) * rstd * lnw[j] + lnb[j];
        o *= at[j];
        orow[j] = o;
        int h = j / CHD, c = j - h * CHD;
        out2[(((size_t)b * NHEAD + h) * SEQ + n) * CHD + c] = o;
    }
}

extern "C" void kernel_launch(void* const* d_in, const int* in_sizes, int n_in,
                              void* d_out, int out_size, void* d_ws, size_t ws_size,
                              hipStream_t stream) {
    const float* x     = (const float*)d_in[0];
    const float* Wq    = (const float*)d_in[1];
    const float* temp  = (const float*)d_in[2];
    const float* fc1w  = (const float*)d_in[3];
    const float* fc1b  = (const float*)d_in[4];
    const float* dww   = (const float*)d_in[5];
    const float* dwb   = (const float*)d_in[6];
    const float* gamma = (const float*)d_in[7];
    const float* fc2w  = (const float*)d_in[8];
    const float* fc2b  = (const float*)d_in[9];
    const float* lnw   = (const float*)d_in[10];
    const float* lnb   = (const float*)d_in[11];

    float* out  = (float*)d_out;
    float* out2 = out + (size_t)BATCH * SEQ * DIM;

    // ws layout:
    //   xb    : [0, 25165824)                      (reused as vpre by fc2)
    //   h1    : [25165824, +100663296)
    //   Bbig  : [125829120, +5898240)   = fc1wb (3072x768) || Wqb (768x768)
    //   fc2wb : [131727360, +4718592)
    //   stats : [136445952, ...)
    char* ws = (char*)d_ws;
    u16* xb     = (u16*)ws;
    u16* h1     = (u16*)(ws + 25165824);
    u16* Bbig   = (u16*)(ws + 125829120);
    u16* Wqb    = Bbig + (size_t)HID * DIM;      // rows 3072..3839 of Bbig
    u16* fc2wb  = (u16*)(ws + 131727360);
    float* Mx   = (float*)(ws + 136445952);
    float* Sx   = Mx + BATCH * DIM;
    float* kp   = Sx + BATCH * DIM;
    float* attnv = kp + BATCH * NHEAD * SEQ;
    u16* vpreb  = xb;                            // reuse after fc1 consumed xb

    // Qb lives in d_out until qattn consumes it; then dwconv overwrites d_out
    // with h2; fc2 consumes h2 before ln_out writes out/out2.
    u16* Qb = (u16*)d_out;
    u16* h2 = (u16*)d_out;

    // ---- fp32 -> bf16 conversions (one kernel) ----
    {
        const int tot4 = (MTOT * DIM + DIM * DIM + HID * DIM + DIM * HID) / 4;
        cvt_all<<<(tot4 + 255) / 256, 256, 0, stream>>>(
            x, Wq, fc1w, fc2w, xb, Wqb, Bbig, fc2wb);
    }

    // ---- merged fc1+Wq GEMM: N = 3840 = 3072 (h1, +fc1b) || 768 (Qb) ----
    gemm128<<<(MTOT / 128) * (3840 / 128), 256, 0, stream>>>(
        xb, Bbig, fc1b, h1, HID, Qb, MTOT, HID + DIM, DIM);

    // ---- attention tail ----
    colsm_stats<<<dim3(DIM / 64, BATCH), 256, 0, stream>>>(xb, Mx, Sx);
    kp_k<<<dim3(SEQ, BATCH), 256, 0, stream>>>(xb, Mx, Sx, kp);
    qattn_k<<<dim3(DIM / 64, BATCH), 256, 0, stream>>>(Qb, kp, temp, attnv);

    // ---- MLP path ----
    dwconv_v<<<dim3(3, 128, BATCH), 128, 0, stream>>>(h1, dww, dwb, gamma, h2);
    gemm128<<<(MTOT / 128) * (DIM / 128), 256, 0, stream>>>(
        h2, fc2wb, fc2b, vpreb, DIM, (u16*)nullptr, MTOT, DIM, HID);
    ln_out_k<<<dim3(SEQ, BATCH), 256, 0, stream>>>(vpreb, lnw, lnb, attnv, out, out2);
}

// Round 13
// 377.569 us; speedup vs baseline: 1.3481x; 1.3481x over previous
//
#include <hip/hip_runtime.h>

// B=16, N=1024 (=32x32), DIM=768, HEADS=8, CH=96, HIDDEN=3072.
#define BATCH 16
#define SEQ   1024
#define DIM   768
#define NHEAD 8
#define CHD   96
#define HID   3072
#define MTOT  (BATCH * SEQ)   // 16384

using u16 = unsigned short;
typedef __attribute__((ext_vector_type(8))) short bf16x8;   // 8 bf16 = 4 VGPRs
typedef __attribute__((ext_vector_type(4))) float f32x4;

#define AS1 __attribute__((address_space(1)))
#define AS3 __attribute__((address_space(3)))

__device__ inline float bf2f(u16 u) {
    union { unsigned int i; float f; } v; v.i = ((unsigned int)u) << 16; return v.f;
}
__device__ inline u16 f2bf(float f) {
    union { float f; unsigned int i; } v; v.f = f;
    unsigned int r = v.i + 0x7FFFu + ((v.i >> 16) & 1u);
    return (u16)(r >> 16);
}

__device__ inline void gld16(const void* g, void* l) {
    __builtin_amdgcn_global_load_lds((AS1 const void*)g, (AS3 void*)l, 16, 0, 0);
}

// ---------------------------------------------------------------------------
// r8 GEMM — measured best (377.8 us total): 256x256, BK=32 in a 4-slot LDS
// ring, counted vmcnt (never 0 in steady state), ONE barrier per K-tile
// (waves drift across the 2 phases -> one wave's MFMA overlaps its
// SIMD-partner's ds_read), setprio around MFMA clusters, 0-conflict
// folded-row LDS swizzle, coalesced LDS-transpose epilogue.
//   C[m,n] = sum_k A[m,k]*B[n,k]; n < N1 -> C1 (+bias[n]), else C2 (+0).
// 512 threads = 8 waves (2 x 4); per-wave output 128 x 64.
// Ring WAR proof: STAGE for t+3 writes slot (t+3)&3 == (t-1)&3; every wave
// drained its slot-(t-1) reads (lgkmcnt(0) in t-1 phase 2) before tile-t's
// entry barrier; STAGE issues after that barrier. vmcnt: 4 glds/tile, at
// tile-t entry outstanding <= 12 (t,t+1,t+2) -> vmcnt(8) proves tile t
// landed for this wave; entry barrier extends to all waves.
// ---------------------------------------------------------------------------
__global__ __launch_bounds__(512) void gemm_p(const u16* __restrict__ A,
                                              const u16* __restrict__ B,
                                              const float* __restrict__ bias,
                                              u16* __restrict__ C1, int N1,
                                              u16* __restrict__ C2,
                                              int M, int N, int K) {
    constexpr int BM = 256;
    constexpr int ASLOT = BM * 32;               // A elems per ring slot
    constexpr int AFOLD = BM / 2;
    constexpr int NFI = BM / 32;                 // 8
    __shared__ u16 lds[4 * (ASLOT + 8192)];      // 128 KB

    const int tid = threadIdx.x;
    const int lane = tid & 63;
    const int wid = tid >> 6;
    const int wm = (wid >> 2) * AFOLD;
    const int wn = (wid & 3) << 6;

    // XCD-chunked bijective swizzle (caller guarantees nwg % 8 == 0).
    const int nwg = gridDim.x;
    const int wg = blockIdx.x;
    const int lid = (wg & 7) * (nwg >> 3) + (wg >> 3);
    const int nbx = N >> 8;
    const int mb = lid / nbx, nb = lid - mb * nbx;
    const int m0 = mb * BM, n0 = nb << 8;

    // ---- staging geometry (pre-swizzled source) ----
    const int sprow = tid >> 3;                  // 0..63
    const int s_l = (tid & 7) ^ (sprow & 7);     // logical slot8
    const int sgk = (s_l & 3) << 3;              // logical k elems
    const u16* pa = A + (size_t)(m0 + (s_l >> 2) * AFOLD + sprow) * K + sgk;
    const u16* pb = B + (size_t)(n0 + (s_l >> 2) * 128 + sprow) * K + sgk;
    const size_t r64K = (size_t)64 * K;

#define STAGE_A(slot, k0) do {                                        \
    gld16(pa + (k0), &lds[(slot) * (ASLOT + 8192) + tid * 8]);        \
    gld16(pa + (k0) + r64K,                                           \
          &lds[(slot) * (ASLOT + 8192) + 4096 + tid * 8]);            \
} while (0)
#define STAGE_B(slot, k0) do {                                        \
    gld16(pb + (k0), &lds[(slot) * (ASLOT + 8192) + ASLOT + tid * 8]);\
    gld16(pb + (k0) + r64K,                                           \
          &lds[(slot) * (ASLOT + 8192) + ASLOT + 4096 + tid * 8]);    \
} while (0)

    // ---- fragment read geometry ----
    const int lrow = lane & 15;
    const int kg = lane >> 4;
    const int xA = (((wid >> 2) * 4 + kg) ^ (lrow & 7)) << 3;
    const int xB = (((wn >> 7) * 4 + kg) ^ (lrow & 7)) << 3;
    const int bbase = (wn & 64) + lrow;

    f32x4 acc[NFI][4] = {};

    const int NT = K >> 5;
    STAGE_A(0, 0);  STAGE_B(0, 0);
    STAGE_A(1, 32); STAGE_B(1, 32);
    STAGE_A(2, 64); STAGE_B(2, 64);

    for (int t = 0; t < NT; ++t) {
        const int rem = NT - 1 - t;
        if (rem >= 2)      asm volatile("s_waitcnt vmcnt(8)" ::: "memory");
        else if (rem == 1) asm volatile("s_waitcnt vmcnt(4)" ::: "memory");
        else               asm volatile("s_waitcnt vmcnt(0)" ::: "memory");
        __builtin_amdgcn_sched_barrier(0);
        __builtin_amdgcn_s_barrier();          // ONE barrier per K-tile

        const u16* Ls = &lds[(t & 3) * (ASLOT + 8192)];
        const int k3 = (t + 3) << 5;

        // ---------------- phase 1 ----------------
        bf16x8 bfr[4], af[NFI / 2];
#pragma unroll
        for (int j = 0; j < 4; ++j)
            bfr[j] = *(const bf16x8*)&Ls[ASLOT + (bbase + j * 16) * 64 + xB];
#pragma unroll
        for (int i = 0; i < NFI / 2; ++i)
            af[i] = *(const bf16x8*)&Ls[(i * 16 + lrow) * 64 + xA];
        if (rem >= 3) STAGE_A((t + 3) & 3, k3);
        asm volatile("s_waitcnt lgkmcnt(0)" ::: "memory");
        __builtin_amdgcn_sched_barrier(0);
        __builtin_amdgcn_s_setprio(1);
#pragma unroll
        for (int i = 0; i < NFI / 2; ++i)
#pragma unroll
            for (int j = 0; j < 4; ++j)
                acc[i][j] = __builtin_amdgcn_mfma_f32_16x16x32_bf16(af[i], bfr[j], acc[i][j], 0, 0, 0);
        __builtin_amdgcn_s_setprio(0);

        // ---------------- phase 2 (no barrier) ----------------
        bf16x8 af2[NFI / 2];
#pragma unroll
        for (int i = 0; i < NFI / 2; ++i)
            af2[i] = *(const bf16x8*)&Ls[((i + NFI / 2) * 16 + lrow) * 64 + xA];
        if (rem >= 3) STAGE_B((t + 3) & 3, k3);
        asm volatile("s_waitcnt lgkmcnt(0)" ::: "memory");
        __builtin_amdgcn_sched_barrier(0);
        __builtin_amdgcn_s_setprio(1);
#pragma unroll
        for (int i = 0; i < NFI / 2; ++i)
#pragma unroll
            for (int j = 0; j < 4; ++j)
                acc[i + NFI / 2][j] = __builtin_amdgcn_mfma_f32_16x16x32_bf16(af2[i], bfr[j], acc[i + NFI / 2][j], 0, 0, 0);
        __builtin_amdgcn_s_setprio(0);
    }
#undef STAGE_A
#undef STAGE_B

    // ---- epilogue: LDS transpose -> coalesced bf16x8 stores ----
    // C/D frag layout: col = lane&15, row = (lane>>4)*4 + reg  [m89/m91]
    __builtin_amdgcn_s_barrier();              // loop fully drained; LDS free
    u16* Ct = lds;                             // [256][256] bf16, slot^=row&7
    const int crow = (lane >> 4) << 2, ccol = lane & 15;
#pragma unroll
    for (int i = 0; i < NFI; ++i) {
#pragma unroll
        for (int j = 0; j < 4; ++j) {
            const int col = wn + j * 16 + ccol;
            const int gn = n0 + col;
            const float bv = (gn < N1 && bias) ? bias[gn] : 0.f;
#pragma unroll
            for (int r = 0; r < 4; ++r) {
                const int row = wm + i * 16 + crow + r;
                const int slot = (col >> 3) ^ (row & 7);
                Ct[row * 256 + slot * 8 + (col & 7)] = f2bf(acc[i][j][r] + bv);
            }
        }
    }
    __builtin_amdgcn_s_barrier();
    const int N2 = N - N1;
#pragma unroll
    for (int k = 0; k < BM / 16; ++k) {
        const int c = tid + (k << 9);
        const int row = c >> 5, s = c & 31;
        bf16x8 v = *(const bf16x8*)&Ct[row * 256 + ((s ^ (row & 7)) << 3)];
        const int gm = m0 + row, gnb = n0 + (s << 3);
        if (gnb < N1)
            *(bf16x8*)&C1[(size_t)gm * N1 + gnb] = v;
        else
            *(bf16x8*)&C2[(size_t)gm * N2 + gnb - N1] = v;
    }
}

// One-shot fp32 -> bf16 convert of all four inputs (x, Wq, fc1w, fc2w).
__global__ __launch_bounds__(256) void cvt_all(const float* __restrict__ x,
                                               const float* __restrict__ Wq,
                                               const float* __restrict__ w1,
                                               const float* __restrict__ w2,
                                               u16* __restrict__ xb,
                                               u16* __restrict__ Wqb,
                                               u16* __restrict__ w1b,
                                               u16* __restrict__ w2b) {
    const int E0 = MTOT * DIM / 4;
    const int E1 = E0 + DIM * DIM / 4;
    const int E2 = E1 + HID * DIM / 4;
    const int E3 = E2 + DIM * HID / 4;
    int i = blockIdx.x * 256 + threadIdx.x;
    if (i >= E3) return;
    const float* in; u16* out; int k;
    if (i < E0)      { in = x;  out = xb;  k = i; }
    else if (i < E1) { in = Wq; out = Wqb; k = i - E0; }
    else if (i < E2) { in = w1; out = w1b; k = i - E1; }
    else             { in = w2; out = w2b; k = i - E2; }
    float4 v = reinterpret_cast<const float4*>(in)[k];
    ushort4 o;
    o.x = f2bf(v.x); o.y = f2bf(v.y); o.z = f2bf(v.z); o.w = f2bf(v.w);
    reinterpret_cast<ushort4*>(out)[k] = o;
}

// Column-wise (over n) online softmax stats (max, sumexp) per (b, j). bf16 in.
__global__ __launch_bounds__(256) void colsm_stats(const u16* __restrict__ X,
                                                   float* __restrict__ Mo,
                                                   float* __restrict__ So) {
    const int tid = threadIdx.x, lane = tid & 63, chunk = tid >> 6;
    const int b = blockIdx.y;
    const int j = blockIdx.x * 64 + lane;
    const u16* p = X + (size_t)b * SEQ * DIM + j;
    float m = -3.0e38f, s = 0.f;
    const int nEnd = (chunk + 1) << 8;
    for (int n = chunk << 8; n < nEnd; ++n) {
        float raw = bf2f(p[(size_t)n * DIM]);
        float nm = fmaxf(m, raw);
        s = s * __expf(m - nm) + __expf(raw - nm);
        m = nm;
    }
    __shared__ float ms[4][64], ss[4][64];
    ms[chunk][lane] = m; ss[chunk][lane] = s;
    __syncthreads();
    if (tid < 64) {
        float M = fmaxf(fmaxf(ms[0][lane], ms[1][lane]), fmaxf(ms[2][lane], ms[3][lane]));
        float S = ss[0][lane] * __expf(ms[0][lane] - M) + ss[1][lane] * __expf(ms[1][lane] - M) +
                  ss[2][lane] * __expf(ms[2][lane] - M) + ss[3][lane] * __expf(ms[3][lane] - M);
        Mo[b * DIM + j] = M;
        So[b * DIM + j] = S;
    }
}

// kp[b,h,n] = mean_c softmax_n(x)[b,n,h*96+c]   (bf16 x)
// 8 heads x 32 lanes; each lane sums 3 channels, 32-wide shuffle reduce.
__global__ __launch_bounds__(256) void kp_k(const u16* __restrict__ x,
                                            const float* __restrict__ Mx,
                                            const float* __restrict__ Sx,
                                            float* __restrict__ kp) {
    const int n = blockIdx.x, b = blockIdx.y, tid = threadIdx.x;
    const u16* row = x + ((size_t)b * SEQ + n) * DIM;
    const int h = tid >> 5, c0 = tid & 31;
    const float* Mrow = Mx + b * DIM;
    const float* Srow = Sx + b * DIM;
    float s = 0.f;
#pragma unroll
    for (int q = 0; q < 3; ++q) {
        const int j = h * CHD + c0 + (q << 5);
        s += __expf(bf2f(row[j]) - Mrow[j]) / Srow[j];
    }
#pragma unroll
    for (int o = 16; o; o >>= 1) s += __shfl_down(s, o, 32);
    if (c0 == 0) kp[((size_t)b * NHEAD + h) * SEQ + n] = s * (1.f / (float)CHD);
}

// Fused column-softmax(Q) + gated attention:
// attn[b,j] = temp[h] * sigmoid( (sum_n exp(Q-M)*kp) / (sum_n exp(Q-M)) )
__global__ __launch_bounds__(256) void qattn_k(const u16* __restrict__ Q,
                                               const float* __restrict__ kp,
                                               const float* __restrict__ temp,
                                               float* __restrict__ attnv) {
    const int tid = threadIdx.x, lane = tid & 63, chunk = tid >> 6;
    const int b = blockIdx.y;
    const int j = blockIdx.x * 64 + lane;
    const int h = j / CHD;
    const u16* qp = Q + (size_t)b * SEQ * DIM + j;
    const float* kpp = kp + ((size_t)b * NHEAD + h) * SEQ;
    float m = -3.0e38f, s = 0.f, a = 0.f;
    const int nEnd = (chunk + 1) << 8;
    for (int n = chunk << 8; n < nEnd; ++n) {
        float q = bf2f(qp[(size_t)n * DIM]);
        float nm = fmaxf(m, q);
        float sc = __expf(m - nm), e = __expf(q - nm);
        s = s * sc + e;
        a = a * sc + e * kpp[n];
        m = nm;
    }
    __shared__ float ms[4][64], ss[4][64], as_[4][64];
    ms[chunk][lane] = m; ss[chunk][lane] = s; as_[chunk][lane] = a;
    __syncthreads();
    if (tid < 64) {
        float M = fmaxf(fmaxf(ms[0][lane], ms[1][lane]), fmaxf(ms[2][lane], ms[3][lane]));
        float S = 0.f, A = 0.f;
#pragma unroll
        for (int c = 0; c < 4; ++c) {
            float sc = __expf(ms[c][lane] - M);
            S += ss[c][lane] * sc;
            A += as_[c][lane] * sc;
        }
        float z = A / S;
        attnv[b * DIM + j] = temp[h] / (1.f + __expf(-z));
    }
}

// Depthwise 3x3 + residual + gamma, vectorized: 8 channels x 8 x-positions
// per thread. Residual/bias folded into weights.
__global__ __launch_bounds__(128) void dwconv_v(const u16* __restrict__ h1,
                                                const float* __restrict__ w,
                                                const float* __restrict__ dwb,
                                                const float* __restrict__ gamma,
                                                u16* __restrict__ h2) {
    const int g = blockIdx.x * 128 + threadIdx.x;   // ch8 group, 0..383
    const int y = blockIdx.y >> 2;                  // 0..31
    const int xw0 = (blockIdx.y & 3) << 3;          // 0,8,16,24
    const int b = blockIdx.z;
    const int ch0 = g << 3;

    float wreg[8][9], bias2[8];
#pragma unroll
    for (int c = 0; c < 8; ++c) {
        const float gm = gamma[ch0 + c];
#pragma unroll
        for (int k = 0; k < 9; ++k) wreg[c][k] = gm * w[(ch0 + c) * 9 + k];
        wreg[c][4] += 1.0f;                 // residual fold (center tap)
        bias2[c] = gm * dwb[ch0 + c];
    }

    float acc[8][8];
#pragma unroll
    for (int xo = 0; xo < 8; ++xo)
#pragma unroll
        for (int c = 0; c < 8; ++c) acc[xo][c] = bias2[c];

    const u16* base = h1 + (size_t)b * SEQ * HID + ch0;
#pragma unroll
    for (int dy = 0; dy < 3; ++dy) {
        const int yy = y + dy - 1;
        if ((unsigned)yy > 31u) continue;           // wave-uniform
#pragma unroll
        for (int cr = -1; cr <= 8; ++cr) {          // column rel to xw0
            const int col = xw0 + cr;
            if ((unsigned)col > 31u) continue;      // wave-uniform
            const uint4 v = *reinterpret_cast<const uint4*>(
                base + (size_t)((yy << 5) + col) * HID);
            float f[8];
            f[0] = bf2f((u16)(v.x & 0xffff)); f[1] = bf2f((u16)(v.x >> 16));
            f[2] = bf2f((u16)(v.y & 0xffff)); f[3] = bf2f((u16)(v.y >> 16));
            f[4] = bf2f((u16)(v.z & 0xffff)); f[5] = bf2f((u16)(v.z >> 16));
            f[6] = bf2f((u16)(v.w & 0xffff)); f[7] = bf2f((u16)(v.w >> 16));
            const int xlo = cr > 0 ? cr - 1 : 0;
            const int xhi = cr < 7 ? cr + 1 : 7;
#pragma unroll
            for (int xo = 0; xo < 8; ++xo) {
                if (xo < xlo || xo > xhi) continue; // compile-time after unroll
                const int dx = cr - xo + 1;
#pragma unroll
                for (int c = 0; c < 8; ++c)
                    acc[xo][c] += f[c] * wreg[c][dy * 3 + dx];
            }
        }
    }

#pragma unroll
    for (int xo = 0; xo < 8; ++xo) {
        const int n = (y << 5) + xw0 + xo;
        uint4 o;
        o.x = (unsigned)f2bf(acc[xo][0]) | ((unsigned)f2bf(acc[xo][1]) << 16);
        o.y = (unsigned)f2bf(acc[xo][2]) | ((unsigned)f2bf(acc[xo][3]) << 16);
        o.z = (unsigned)f2bf(acc[xo][4]) | ((unsigned)f2bf(acc[xo][5]) << 16);
        o.w = (unsigned)f2bf(acc[xo][6]) | ((unsigned)f2bf(acc[xo][7]) << 16);
        *reinterpret_cast<uint4*>(h2 + ((size_t)b * SEQ + n) * HID + ch0) = o;
    }
}

// LayerNorm(768) then out[b,n,j] = attn[b,j]*v ; out2[b,h,n,c] = same value.
__global__ __launch_bounds__(256) void ln_out_k(const u16* __restrict__ vpre,
                                                const float* __restrict__ lnw,
                                                const float* __restrict__ lnb,
                                                const float* __restrict__ attnv,
                                                float* __restrict__ out,
                                                float* __restrict__ out2) {
    const int n = blockIdx.x, b = blockIdx.y, tid = threadIdx.x;
    __shared__ float red[4];
    const u16* row = vpre + ((size_t)b * SEQ + n) * DIM;
    float v[3];
    float s = 0.f;
#pragma unroll
    for (int q = 0; q < 3; ++q) { v[q] = bf2f(row[tid + (q << 8)]); s += v[q]; }
#pragma unroll
    for (int o = 32; o; o >>= 1) s += __shfl_down(s, o, 64);
    if ((tid & 63) == 0) red[tid >> 6] = s;
    __syncthreads();
    const float mu = (red[0] + red[1] + red[2] + red[3]) * (1.f / (float)DIM);
    __syncthreads();
    float vs = 0.f;
#pragma unroll
    for (int q = 0; q < 3; ++q) { float d = v[q] - mu; vs += d * d; }
#pragma unroll
    for (int o = 32; o; o >>= 1) vs += __shfl_down(vs, o, 64);
    if ((tid & 63) == 0) red[tid >> 6] = vs;
    __syncthreads();
    const float rstd = rsqrtf((red[0] + red[1] + red[2] + red[3]) * (1.f / (float)DIM) + 1e-5f);
    const float* at = attnv + b * DIM;
    float* orow = out + ((size_t)b * SEQ + n) * DIM;
#pragma unroll
    for (int q = 0; q < 3; ++q) {
        int j = tid + (q << 8);
        float o = (v[q] - mu) * rstd * lnw[j] + lnb[j];
        o *= at[j];
        orow[j] = o;
        int h = j / CHD, c = j - h * CHD;
        out2[(((size_t)b * NHEAD + h) * SEQ + n) * CHD + c] = o;
    }
}

extern "C" void kernel_launch(void* const* d_in, const int* in_sizes, int n_in,
                              void* d_out, int out_size, void* d_ws, size_t ws_size,
                              hipStream_t stream) {
    const float* x     = (const float*)d_in[0];
    const float* Wq    = (const float*)d_in[1];
    const float* temp  = (const float*)d_in[2];
    const float* fc1w  = (const float*)d_in[3];
    const float* fc1b  = (const float*)d_in[4];
    const float* dww   = (const float*)d_in[5];
    const float* dwb   = (const float*)d_in[6];
    const float* gamma = (const float*)d_in[7];
    const float* fc2w  = (const float*)d_in[8];
    const float* fc2b  = (const float*)d_in[9];
    const float* lnw   = (const float*)d_in[10];
    const float* lnb   = (const float*)d_in[11];

    float* out  = (float*)d_out;
    float* out2 = out + (size_t)BATCH * SEQ * DIM;

    // ws layout:
    //   xb    : [0, 25165824)                      (reused as vpre by fc2)
    //   h1    : [25165824, +100663296)
    //   Bbig  : [125829120, +5898240)   = fc1wb (3072x768) || Wqb (768x768)
    //   fc2wb : [131727360, +4718592)
    //   stats : [136445952, ...)
    char* ws = (char*)d_ws;
    u16* xb     = (u16*)ws;
    u16* h1     = (u16*)(ws + 25165824);
    u16* Bbig   = (u16*)(ws + 125829120);
    u16* Wqb    = Bbig + (size_t)HID * DIM;      // rows 3072..3839 of Bbig
    u16* fc2wb  = (u16*)(ws + 131727360);
    float* Mx   = (float*)(ws + 136445952);
    float* Sx   = Mx + BATCH * DIM;
    float* kp   = Sx + BATCH * DIM;
    float* attnv = kp + BATCH * NHEAD * SEQ;
    u16* vpreb  = xb;                            // reuse after fc1 consumed xb

    // Qb lives in d_out until qattn consumes it; then dwconv overwrites d_out
    // with h2; fc2 consumes h2 before ln_out writes out/out2.
    u16* Qb = (u16*)d_out;
    u16* h2 = (u16*)d_out;

    // ---- fp32 -> bf16 conversions (one kernel) ----
    {
        const int tot4 = (MTOT * DIM + DIM * DIM + HID * DIM + DIM * HID) / 4;
        cvt_all<<<(tot4 + 255) / 256, 256, 0, stream>>>(
            x, Wq, fc1w, fc2w, xb, Wqb, Bbig, fc2wb);
    }

    // ---- merged fc1+Wq GEMM: N = 3840 = 3072 (h1, +fc1b) || 768 (Qb) ----
    gemm_p<<<(MTOT / 256) * (3840 / 256), 512, 0, stream>>>(
        xb, Bbig, fc1b, h1, HID, Qb, MTOT, HID + DIM, DIM);

    // ---- attention tail ----
    colsm_stats<<<dim3(DIM / 64, BATCH), 256, 0, stream>>>(xb, Mx, Sx);
    kp_k<<<dim3(SEQ, BATCH), 256, 0, stream>>>(xb, Mx, Sx, kp);
    qattn_k<<<dim3(DIM / 64, BATCH), 256, 0, stream>>>(Qb, kp, temp, attnv);

    // ---- MLP path ----
    dwconv_v<<<dim3(3, 128, BATCH), 128, 0, stream>>>(h1, dww, dwb, gamma, h2);
    gemm_p<<<(MTOT / 256) * (DIM / 256), 512, 0, stream>>>(
        h2, fc2wb, fc2b, vpreb, DIM, (u16*)nullptr, MTOT, DIM, HID);
    ln_out_k<<<dim3(SEQ, BATCH), 256, 0, stream>>>(vpreb, lnw, lnb, attnv, out, out2);
}